// Round 21
// baseline (1093.857 us; speedup 1.0000x reference)
//
#include <hip/hip_runtime.h>

#define NN 50000
#define NE 800000
#define NG 128
#define NB_SCAN 196        // ceil(NN/256)
#define PADW 0xC1000000u   // bits of -8.0f : pad coords -> weight exactly 0

typedef unsigned int uint;
typedef unsigned short ushort;
typedef __attribute__((ext_vector_type(8))) short short8;
typedef __attribute__((ext_vector_type(4))) float f32x4;
typedef __attribute__((ext_vector_type(16))) float f32x16;

__device__ __forceinline__ float bf2f(ushort u){ union{uint i; float f;} v; v.i=(uint)u<<16; return v.f; }
__device__ __forceinline__ ushort f2bf(float f){ union{float f; uint i;} v; v.f=f; return (ushort)((v.i + 0x7FFFu + ((v.i>>16)&1u))>>16); }
__device__ __forceinline__ int iswz(int i){ return i ^ ((i>>4)&3); }   // granule swizzle, involution

// ---------------- zero scratch re-initialized every call ----------------
__global__ void zero_k(int* hist, float* pooled, int* gcnt, int* bcnt){
    int i = blockIdx.x*blockDim.x + threadIdx.x;
    if (i < NN) hist[i] = 0;
    if (i < NG*64) pooled[i] = 0.f;
    if (i < NG) gcnt[i] = 0;
    if (i < 16) bcnt[i] = 0;
}

// ---------------- dst histogram ----------------
__global__ void hist_k(const int* __restrict__ ei, int* __restrict__ hist){
    int e = blockIdx.x*blockDim.x + threadIdx.x;
    if (e < NE) atomicAdd(&hist[ei[NE + e]], 1);
}

// ---------------- hierarchical exclusive scan ----------------
__global__ __launch_bounds__(256) void scan1(const int* __restrict__ hist, int* __restrict__ bsum){
    __shared__ int sm[256];
    int t = threadIdx.x, i = blockIdx.x*256 + t;
    sm[t] = (i < NN) ? hist[i] : 0;
    __syncthreads();
    for (int o = 128; o > 0; o >>= 1){ if (t < o) sm[t] += sm[t+o]; __syncthreads(); }
    if (t == 0) bsum[blockIdx.x] = sm[0];
}
__global__ __launch_bounds__(256) void scan2(const int* __restrict__ bsum, int* __restrict__ bpre){
    __shared__ int sm[256];
    int t = threadIdx.x;
    int v = (t < NB_SCAN) ? bsum[t] : 0;
    sm[t] = v; __syncthreads();
    int acc = v;
    for (int o = 1; o < 256; o <<= 1){
        int u = (t >= o) ? sm[t-o] : 0; __syncthreads();
        acc += u; sm[t] = acc; __syncthreads();
    }
    if (t < NB_SCAN) bpre[t] = acc - v;
}
__global__ __launch_bounds__(256) void scan3(const int* __restrict__ hist, const int* __restrict__ bpre,
                                             int* __restrict__ offs, int* __restrict__ cursor,
                                             float* __restrict__ invc, int* __restrict__ bcnt){
    __shared__ int sm[256];
    int t = threadIdx.x, b = blockIdx.x, i = b*256 + t;
    int v = (i < NN) ? hist[i] : 0;
    sm[t] = v; __syncthreads();
    int acc = v;
    for (int o = 1; o < 256; o <<= 1){
        int u = (t >= o) ? sm[t-o] : 0; __syncthreads();
        acc += u; sm[t] = acc; __syncthreads();
    }
    int excl = acc - v + bpre[b];
    if (i < NN){
        offs[i] = excl; cursor[i] = excl; invc[i] = 1.0f/(float)max(v,1);
        int sv = (v + 15) >> 4; if (sv > 15) sv = 15;
        atomicAdd(&bcnt[sv], 1);
    }
    if (i == NN-1) offs[NN] = NE;
}

// ---------------- degree buckets: prefix + node scatter (perm) ----------------
__global__ void bpfx(const int* __restrict__ bcnt, int* __restrict__ bcur){
    if (threadIdx.x == 0){
        int run = 0;
        for (int k = 0; k < 16; ++k){ bcur[k] = run; run += bcnt[k]; }
    }
}
__global__ void bscat(const int* __restrict__ hist, int* __restrict__ bcur, int* __restrict__ perm){
    int d = blockIdx.x*blockDim.x + threadIdx.x;
    if (d >= NN) return;
    int sv = (hist[d] + 15) >> 4; if (sv > 15) sv = 15;
    int pos = atomicAdd(&bcur[sv], 1);
    perm[pos] = d;
}

// ---------------- counting sort: payload = {meta, px, py, 0} (16B) ----------------
__global__ void scatter_k(const int* __restrict__ ei, const float* __restrict__ pseudo,
                          int* __restrict__ cursor, uint4* __restrict__ payA){
    int e = blockIdx.x*blockDim.x + threadIdx.x;
    if (e >= NE) return;
    float2 ps = *(const float2*)(pseudo + 2*(size_t)e);
    float px = ps.x * 4.0f, py = ps.y * 4.0f;
    int lx = min(max((int)floorf(px), 0), 3);
    int ly = min(max((int)floorf(py), 0), 3);
    uint meta = (uint)ei[e] | ((uint)lx<<16) | ((uint)ly<<18);   // src < 65536
    int pos = atomicAdd(&cursor[ei[NE + e]], 1);
    payA[pos] = make_uint4(meta, __float_as_uint(px), __float_as_uint(py), 0u);
}

// ---------------- pack [Wflat;root] into MFMA B-fragment layout, bf16 ----------------
template<int IN>
__global__ void wprep_k(const float* __restrict__ W, const float* __restrict__ root, ushort* __restrict__ Bp){
    const int total = 26*IN*64;
    int tid = blockIdx.x*blockDim.x + threadIdx.x;
    if (tid >= total) return;
    int j    = tid & 7;
    int lane = (tid >> 3) & 63;
    int ctkt = tid >> 9;
    int ct   = ctkt & 3;
    int kt   = ctkt >> 2;
    int kk   = kt*32 + (lane>>4)*8 + j;
    int col  = ct*16 + (lane & 15);
    float v;
    if (kk < 25*IN){ int k = kk / IN; int i = kk % IN; v = W[((size_t)k*IN + i)*64 + col]; }
    else           { v = root[(size_t)(kk - 25*IN)*64 + col]; }
    Bp[tid] = f2bf(v);
}

// ---------------- layer 1: CSR reduce, unroll-4 batched loads ----------------
__global__ __launch_bounds__(256) void reduce1_k(const float* __restrict__ x, const uint4* __restrict__ payA,
                                                 const int* __restrict__ offs, const float* __restrict__ invc,
                                                 const float* __restrict__ W1, const float* __restrict__ root1,
                                                 const float* __restrict__ b1, ushort* __restrict__ h1bf){
    __shared__ float w1s[25*32];
    for (int i = threadIdx.x; i < 25*32; i += 256) w1s[i] = W1[i];
    __syncthreads();
    int wid  = threadIdx.x >> 6;
    int lane = threadIdx.x & 63;
    int o    = lane & 31;
    int half = lane >> 5;
    int d    = blockIdx.x*4 + wid;
    int s = offs[d], e = offs[d+1];
    float acc = 0.f;
#define E1(QA, XS) { uint meta = (QA).x; \
    int lx = (meta>>16)&3, ly = (meta>>18)&3; \
    float px = __uint_as_float((QA).y), py = __uint_as_float((QA).z); \
    float fx = px - (float)lx, fy = py - (float)ly; \
    float gx = 1.f - fx, gy = 1.f - fy; \
    float wa = half ? fx*gy : gx*gy; \
    float wb = half ? fx*fy : gx*fy; \
    int ka = ly*5 + lx + half; \
    acc += (wa*w1s[ka*32 + o] + wb*w1s[(ka+5)*32 + o]) * (XS); }
    int p = s;
    for (; p + 4 <= e; p += 4){
        uint4 a0 = payA[p], a1 = payA[p+1], a2 = payA[p+2], a3 = payA[p+3];
        float x0 = x[a0.x & 0xFFFF], x1 = x[a1.x & 0xFFFF];
        float x2 = x[a2.x & 0xFFFF], x3 = x[a3.x & 0xFFFF];
        E1(a0, x0) E1(a1, x1) E1(a2, x2) E1(a3, x3)
    }
    for (; p < e; ++p){
        uint4 a0 = payA[p];
        float x0 = x[a0.x & 0xFFFF];
        E1(a0, x0)
    }
#undef E1
    acc += __shfl_xor(acc, 32);
    if (half == 0){
        float val = acc*invc[d] + x[d]*root1[o] + b1[o];
        val = val > 0.f ? val : expm1f(val);
        h1bf[(size_t)d*32 + o] = f2bf(val);
    }
}

// weight for spline row (i0,j0): closed-form saturated linear, round-to-nearest bf16
#define WCALC(Q0, AH) { \
    float px_ = __uint_as_float((Q0).y), py_ = __uint_as_float((Q0).z); \
    float wx_ = fmaxf(1.f - fabsf(px_ - fi0), 0.f); \
    float wy_ = fmaxf(1.f - fabsf(py_ - fj0), 0.f); \
    (AH) = (short)f2bf(wx_ * wy_); }

// async payload staging: global_load_lds 16B/lane (lanes 0..rem-1), PAD prefill for tail lanes
#define STAGE(BUF, STEP) { \
    int rem_ = h - (STEP)*16; if (rem_ > 16) rem_ = 16; \
    if (lane < 16 && lane >= rem_) eA[w][BUF][lane] = PAD4; \
    if (lane < rem_){ \
        __builtin_amdgcn_global_load_lds( \
            (const __attribute__((address_space(1))) void*)(payA + (size_t)s + (STEP)*16 + lane), \
            (__attribute__((address_space(3))) void*)&eA[w][BUF][lane], 16, 0, 0); \
    } }

// ---------------- fused layer IN=32: 16 bucketed nodes/block ----------------
template<int MODE>
__global__ __launch_bounds__(512) void fused32(
        const ushort* __restrict__ hin, const uint4* __restrict__ payA,
        const int* __restrict__ offs, const float* __restrict__ invc,
        const int* __restrict__ perm,
        const ushort* __restrict__ Bp, const float* __restrict__ bias,
        const int* __restrict__ batch, ushort* __restrict__ hout,
        float* __restrict__ pooled, int* __restrict__ gcnt)
{
    constexpr int KT = 26, KH = 13;
    __shared__ __align__(16) ushort Sb[KT*512];
    __shared__ __align__(16) uint4 eA[8][2][16];
    __shared__ float red[1024];
    __shared__ float outS[1024];
    __shared__ int pdS[16];

    const int tid = threadIdx.x, lane = tid & 63, w = tid >> 6;
    const int ln31 = lane & 31, kg2 = lane >> 5;
    const int d0 = blockIdx.x * 16;
    const float fi0 = (float)(ln31 % 5), fj0 = (float)(ln31 / 5);
    const uint4 PAD4 = make_uint4(0u, PADW, PADW, 0u);

    if (tid < 16) pdS[tid] = perm[d0 + tid];

    for (int nn = 0; nn < 2; ++nn){
        const int node = w*2 + nn;
        const int d = perm[d0 + node];
        int s = offs[d];
        int h = offs[d+1] - s;
        int steps = (h + 15) >> 4;

        f32x16 accH;
        #pragma unroll
        for (int q = 0; q < 16; ++q) accH[q] = 0.f;

        if (steps > 0) STAGE(0, 0)
        for (int ks = 0; ks < steps; ++ks){
            int cb = ks & 1;
            if (ks+1 < steps){
                STAGE(cb^1, ks+1)
                asm volatile("s_waitcnt vmcnt(1)" ::: "memory");
            } else {
                asm volatile("s_waitcnt vmcnt(0)" ::: "memory");
            }
            __builtin_amdgcn_sched_barrier(0);
            short8 ah; short8 bfv;
            #pragma unroll
            for (int j = 0; j < 8; ++j){
                uint4 q0 = eA[w][cb][kg2*8 + j];
                WCALC(q0, ah[j])
                bfv[j] = (short)hin[(size_t)(q0.x & 0xFFFFu)*32 + ln31];
            }
            accH = __builtin_amdgcn_mfma_f32_32x32x16_bf16(ah, bfv, accH, 0, 0, 0);
        }

        {
            float ic = invc[d];
            int jd  = ln31 & 7;
            int l3  = ln31 >> 3;
            #pragma unroll
            for (int reg = 0; reg < 16; ++reg){
                int r = (reg & 3) + 8*(reg >> 2) + 4*kg2;
                if (r < 25)
                    Sb[r*512 + iswz(l3*16 + node)*8 + jd] = f2bf(accH[reg]*ic);
            }
            if (lane < 32)
                Sb[25*512 + iswz(((lane>>3)&3)*16 + node)*8 + (lane&7)] = hin[(size_t)d*32 + lane];
        }
    }
    __syncthreads();

    {
        int ct = w & 3, kh = w >> 2;
        int c15 = lane & 15, kg = lane >> 4;
        int ig = iswz(lane);
        f32x4 a4 = {0.f,0.f,0.f,0.f};
        const ushort* bb = Bp + ct*512 + (size_t)lane*8;
        #pragma unroll
        for (int k = 0; k < KH; ++k){
            int kt = kh*KH + k;
            short8 a = *(const short8*)(Sb + kt*512 + ig*8);
            short8 b = *(const short8*)(bb + (size_t)kt*2048);
            a4 = __builtin_amdgcn_mfma_f32_16x16x32_bf16(a, b, a4, 0, 0, 0);
        }
        if (kh == 1){
            float* rr = red + (ct*64 + lane)*4;
            rr[0]=a4[0]; rr[1]=a4[1]; rr[2]=a4[2]; rr[3]=a4[3];
        }
        __syncthreads();
        if (kh == 0){
            const float* rr = red + (ct*64 + lane)*4;
            int col = ct*16 + c15;
            float bs = bias[col];
            #pragma unroll
            for (int jq = 0; jq < 4; ++jq){
                int r16 = kg*4 + jq;
                float v = a4[jq] + rr[jq] + bs;
                v = v > 0.f ? v : expm1f(v);
                if (MODE == 0) ((ushort*)outS)[r16*64 + col] = f2bf(v);
                else           outS[r16*64 + col] = v;
            }
        }
    }
    __syncthreads();

    if (MODE == 0){
        int row = tid >> 5, c2 = tid & 31;
        ((uint*)hout)[(size_t)pdS[row]*32 + c2] = ((const uint*)outS)[tid];
    } else {
        if (w == 0){
            #pragma unroll
            for (int r = 0; r < 16; ++r)
                atomicAdd(&pooled[batch[pdS[r]]*64 + lane], outS[r*64 + lane]);
        } else if (w == 1 && lane < 16){
            atomicAdd(&gcnt[batch[pdS[lane]]], 1);
        }
    }
}

// ---------------- fused layer IN=64: 16 bucketed nodes/block + paired features ----------------
template<int MODE>
__global__ __launch_bounds__(512) void fused64(
        const ushort* __restrict__ hin, const uint4* __restrict__ payA,
        const int* __restrict__ offs, const float* __restrict__ invc,
        const int* __restrict__ perm,
        const ushort* __restrict__ Bp, const float* __restrict__ bias,
        const int* __restrict__ batch, ushort* __restrict__ hout,
        float* __restrict__ pooled, int* __restrict__ gcnt)
{
    constexpr int KT = 52, KH = 26;
    __shared__ __align__(16) ushort Sb[KT*512];
    __shared__ __align__(16) uint4 eA[8][2][16];
    __shared__ float red[1024];
    __shared__ float outS[1024];
    __shared__ int pdS[16];

    const int tid = threadIdx.x, lane = tid & 63, w = tid >> 6;
    const int ln31 = lane & 31, kg2 = lane >> 5;
    const int d0 = blockIdx.x * 16;
    const float fi0 = (float)(ln31 % 5), fj0 = (float)(ln31 / 5);
    const uint4 PAD4 = make_uint4(0u, PADW, PADW, 0u);

    if (tid < 16) pdS[tid] = perm[d0 + tid];

    for (int nn = 0; nn < 2; ++nn){
        const int node = w*2 + nn;
        const int d = perm[d0 + node];
        int s = offs[d];
        int h = offs[d+1] - s;
        int steps = (h + 15) >> 4;

        f32x16 acc0, acc1;
        #pragma unroll
        for (int q = 0; q < 16; ++q){ acc0[q] = 0.f; acc1[q] = 0.f; }

        if (steps > 0) STAGE(0, 0)
        for (int ks = 0; ks < steps; ++ks){
            int cb = ks & 1;
            if (ks+1 < steps){
                STAGE(cb^1, ks+1)
                asm volatile("s_waitcnt vmcnt(1)" ::: "memory");
            } else {
                asm volatile("s_waitcnt vmcnt(0)" ::: "memory");
            }
            __builtin_amdgcn_sched_barrier(0);
            short8 ah; uint hx[8];
            #pragma unroll
            for (int j = 0; j < 8; ++j){
                uint4 q0 = eA[w][cb][kg2*8 + j];
                WCALC(q0, ah[j])
                hx[j] = *(const uint*)(hin + (size_t)(q0.x & 0xFFFFu)*64 + 2*ln31);
            }
            short8 b0, b1;
            #pragma unroll
            for (int j = 0; j < 8; ++j){
                b0[j] = (short)(ushort)hx[j];
                b1[j] = (short)(ushort)(hx[j] >> 16);
            }
            acc0 = __builtin_amdgcn_mfma_f32_32x32x16_bf16(ah, b0, acc0, 0, 0, 0);
            acc1 = __builtin_amdgcn_mfma_f32_32x32x16_bf16(ah, b1, acc1, 0, 0, 0);
        }

        // deposit: acc0/acc1 hold S[r][2*ln31] / S[r][2*ln31+1]
        {
            float ic = invc[d];
            int off0 = 2*ln31;
            int fhi  = ln31 >> 4;
            int kgp  = (off0 >> 3) & 3;
            int jd0  = off0 & 7;
            int gsl  = iswz(kgp*16 + node)*8;
            #pragma unroll
            for (int reg = 0; reg < 16; ++reg){
                int r = (reg & 3) + 8*(reg >> 2) + 4*kg2;
                if (r < 25){
                    int kt = r*2 + fhi;
                    uint pk = (uint)f2bf(acc0[reg]*ic) | ((uint)f2bf(acc1[reg]*ic) << 16);
                    *(uint*)(Sb + kt*512 + gsl + jd0) = pk;
                }
            }
            int f = lane;
            Sb[(50 + (f>>5))*512 + iswz(((f>>3)&3)*16 + node)*8 + (f&7)] = hin[(size_t)d*64 + f];
        }
    }
    __syncthreads();

    // node-GEMM: 8 waves = 4 col-tiles x 2 K-halves, M=16
    {
        int ct = w & 3, kh = w >> 2;
        int c15 = lane & 15, kg = lane >> 4;
        int ig = iswz(lane);
        f32x4 a4 = {0.f,0.f,0.f,0.f};
        const ushort* bb = Bp + ct*512 + (size_t)lane*8;
        #pragma unroll
        for (int k = 0; k < KH; ++k){
            int kt = kh*KH + k;
            short8 a = *(const short8*)(Sb + kt*512 + ig*8);
            short8 b = *(const short8*)(bb + (size_t)kt*2048);
            a4 = __builtin_amdgcn_mfma_f32_16x16x32_bf16(a, b, a4, 0, 0, 0);
        }
        if (kh == 1){
            float* rr = red + (ct*64 + lane)*4;
            rr[0]=a4[0]; rr[1]=a4[1]; rr[2]=a4[2]; rr[3]=a4[3];
        }
        __syncthreads();
        if (kh == 0){
            const float* rr = red + (ct*64 + lane)*4;
            int col = ct*16 + c15;
            float bs = bias[col];
            #pragma unroll
            for (int jq = 0; jq < 4; ++jq){
                int r16 = kg*4 + jq;
                float v = a4[jq] + rr[jq] + bs;
                v = v > 0.f ? v : expm1f(v);
                if (MODE == 0) ((ushort*)outS)[r16*64 + col] = f2bf(v);
                else           outS[r16*64 + col] = v;
            }
        }
    }
    __syncthreads();

    // ---- output ----
    if (MODE == 0){
        int row = tid >> 5, c2 = tid & 31;
        ((uint*)hout)[(size_t)pdS[row]*32 + c2] = ((const uint*)outS)[tid];
    } else {
        if (w == 0){
            #pragma unroll
            for (int r = 0; r < 16; ++r)
                atomicAdd(&pooled[batch[pdS[r]]*64 + lane], outS[r*64 + lane]);
        } else if (w == 1 && lane < 16){
            atomicAdd(&gcnt[batch[pdS[lane]]], 1);
        }
    }
}

// ---------------- head: graph mean-pool -> fc -> log_softmax ----------------
__global__ __launch_bounds__(128) void head_k(const float* __restrict__ pooled, const int* __restrict__ gcnt,
                                              const float* __restrict__ fcw, const float* __restrict__ fcb,
                                              float* __restrict__ out){
    int g = threadIdx.x;
    if (g >= NG) return;
    float inv = 1.0f / fmaxf((float)gcnt[g], 1.0f);
    float logits[10];
    #pragma unroll
    for (int c = 0; c < 10; ++c) logits[c] = fcb[c];
    for (int o = 0; o < 64; ++o){
        float m = pooled[g*64 + o] * inv;
        #pragma unroll
        for (int c = 0; c < 10; ++c) logits[c] += m * fcw[o*10 + c];
    }
    float mx = logits[0];
    #pragma unroll
    for (int c = 1; c < 10; ++c) mx = fmaxf(mx, logits[c]);
    float ssum = 0.f;
    #pragma unroll
    for (int c = 0; c < 10; ++c) ssum += expf(logits[c] - mx);
    float lse = logf(ssum) + mx;
    #pragma unroll
    for (int c = 0; c < 10; ++c) out[g*10 + c] = logits[c] - lse;
}

extern "C" void kernel_launch(void* const* d_in, const int* in_sizes, int n_in,
                              void* d_out, int out_size, void* d_ws, size_t ws_size,
                              hipStream_t stream) {
    const float* x      = (const float*)d_in[0];
    const float* pseudo = (const float*)d_in[2];
    const int*   ei     = (const int*)  d_in[3];
    const int*   batch  = (const int*)  d_in[4];
    const float* W1     = (const float*)d_in[5];
    const float* root1  = (const float*)d_in[6];
    const float* b1     = (const float*)d_in[7];
    const float* W2     = (const float*)d_in[8];
    const float* root2  = (const float*)d_in[9];
    const float* b2     = (const float*)d_in[10];
    const float* W3     = (const float*)d_in[11];
    const float* root3  = (const float*)d_in[12];
    const float* b3     = (const float*)d_in[13];
    const float* fcw    = (const float*)d_in[14];
    const float* fcb    = (const float*)d_in[15];
    float* out = (float*)d_out;

    char* ws = (char*)d_ws;
    size_t off = 0;
    auto alloc = [&](size_t bytes)->char*{ char* p = ws + off; off += (bytes + 255) / 256 * 256; return p; };
    uint4*  payA   = (uint4*) alloc((size_t)NE*16);
    ushort* h1bf   = (ushort*)alloc((size_t)NN*32*2);
    ushort* h2bf   = (ushort*)alloc((size_t)NN*64*2);
    int*    hist   = (int*)   alloc((size_t)NN*4);
    int*    offs   = (int*)   alloc((size_t)(NN+1)*4);
    int*    cursor = (int*)   alloc((size_t)NN*4);
    float*  invc   = (float*) alloc((size_t)NN*4);
    int*    bsum   = (int*)   alloc((size_t)NB_SCAN*4);
    int*    bpre   = (int*)   alloc((size_t)NB_SCAN*4);
    int*    bcnt   = (int*)   alloc((size_t)16*4);
    int*    bcur   = (int*)   alloc((size_t)16*4);
    int*    perm   = (int*)   alloc((size_t)NN*4);
    ushort* Bp2    = (ushort*)alloc((size_t)26*2048*2);
    ushort* Bp3    = (ushort*)alloc((size_t)52*2048*2);
    float*  pooled = (float*) alloc((size_t)NG*64*4);
    int*    gcnt   = (int*)   alloc((size_t)NG*4);
    (void)ws_size; (void)in_sizes; (void)n_in; (void)out_size;

    zero_k   <<<NB_SCAN, 256, 0, stream>>>(hist, pooled, gcnt, bcnt);
    hist_k   <<<(NE+255)/256, 256, 0, stream>>>(ei, hist);
    scan1    <<<NB_SCAN, 256, 0, stream>>>(hist, bsum);
    scan2    <<<1, 256, 0, stream>>>(bsum, bpre);
    scan3    <<<NB_SCAN, 256, 0, stream>>>(hist, bpre, offs, cursor, invc, bcnt);
    bpfx     <<<1, 64, 0, stream>>>(bcnt, bcur);
    bscat    <<<NB_SCAN, 256, 0, stream>>>(hist, bcur, perm);
    scatter_k<<<(NE+255)/256, 256, 0, stream>>>(ei, pseudo, cursor, payA);
    wprep_k<32><<<(26*32*64 + 255)/256, 256, 0, stream>>>(W2, root2, Bp2);
    wprep_k<64><<<(26*64*64 + 255)/256, 256, 0, stream>>>(W3, root3, Bp3);
    reduce1_k<<<NN/4, 256, 0, stream>>>(x, payA, offs, invc, W1, root1, b1, h1bf);
    fused32<0><<<NN/16, 512, 0, stream>>>(h1bf, payA, offs, invc, perm, Bp2, b2, batch, h2bf, pooled, gcnt);
    fused64<1><<<NN/16, 512, 0, stream>>>(h2bf, payA, offs, invc, perm, Bp3, b3, batch, h2bf, pooled, gcnt);
    head_k   <<<1, 128, 0, stream>>>(pooled, gcnt, fcw, fcb, out);
}

// Round 22
// 351.153 us; speedup vs baseline: 3.1150x; 3.1150x over previous
//
#include <hip/hip_runtime.h>

#define NN 50000
#define NE 800000
#define NG 128
#define NB_SCAN 196        // ceil(NN/256)
#define PADW 0xC1000000u   // bits of -8.0f : pad coords -> weight exactly 0

typedef unsigned int uint;
typedef unsigned short ushort;
typedef __attribute__((ext_vector_type(8))) short short8;
typedef __attribute__((ext_vector_type(4))) float f32x4;
typedef __attribute__((ext_vector_type(16))) float f32x16;

__device__ __forceinline__ float bf2f(ushort u){ union{uint i; float f;} v; v.i=(uint)u<<16; return v.f; }
__device__ __forceinline__ ushort f2bf(float f){ union{float f; uint i;} v; v.f=f; return (ushort)((v.i + 0x7FFFu + ((v.i>>16)&1u))>>16); }
__device__ __forceinline__ int iswz(int i){ return i ^ ((i>>4)&3); }   // granule swizzle, involution

// ---------------- zero scratch re-initialized every call ----------------
__global__ void zero_k(int* hist, float* pooled, int* gcnt, int* bcnt){
    int i = blockIdx.x*blockDim.x + threadIdx.x;
    if (i < NN) hist[i] = 0;
    if (i < NG*64) pooled[i] = 0.f;
    if (i < NG) gcnt[i] = 0;
    if (i < 16) bcnt[i] = 0;
}

// ---------------- dst histogram ----------------
__global__ void hist_k(const int* __restrict__ ei, int* __restrict__ hist){
    int e = blockIdx.x*blockDim.x + threadIdx.x;
    if (e < NE) atomicAdd(&hist[ei[NE + e]], 1);
}

// ---------------- hierarchical exclusive scan ----------------
__global__ __launch_bounds__(256) void scan1(const int* __restrict__ hist, int* __restrict__ bsum){
    __shared__ int sm[256];
    int t = threadIdx.x, i = blockIdx.x*256 + t;
    sm[t] = (i < NN) ? hist[i] : 0;
    __syncthreads();
    for (int o = 128; o > 0; o >>= 1){ if (t < o) sm[t] += sm[t+o]; __syncthreads(); }
    if (t == 0) bsum[blockIdx.x] = sm[0];
}
__global__ __launch_bounds__(256) void scan2(const int* __restrict__ bsum, int* __restrict__ bpre){
    __shared__ int sm[256];
    int t = threadIdx.x;
    int v = (t < NB_SCAN) ? bsum[t] : 0;
    sm[t] = v; __syncthreads();
    int acc = v;
    for (int o = 1; o < 256; o <<= 1){
        int u = (t >= o) ? sm[t-o] : 0; __syncthreads();
        acc += u; sm[t] = acc; __syncthreads();
    }
    if (t < NB_SCAN) bpre[t] = acc - v;
}
__global__ __launch_bounds__(256) void scan3(const int* __restrict__ hist, const int* __restrict__ bpre,
                                             int* __restrict__ offs, int* __restrict__ cursor,
                                             float* __restrict__ invc, int* __restrict__ bcnt){
    __shared__ int sm[256];
    __shared__ int wcnt[4][16];
    int t = threadIdx.x, b = blockIdx.x, i = b*256 + t;
    int lane = t & 63, wv = t >> 6;
    int v = (i < NN) ? hist[i] : 0;
    sm[t] = v; __syncthreads();
    int acc = v;
    for (int o = 1; o < 256; o <<= 1){
        int u = (t >= o) ? sm[t-o] : 0; __syncthreads();
        acc += u; sm[t] = acc; __syncthreads();
    }
    int excl = acc - v + bpre[b];
    int sv = 16;
    if (i < NN){
        offs[i] = excl; cursor[i] = excl; invc[i] = 1.0f/(float)max(v,1);
        sv = (v + 15) >> 4; if (sv > 15) sv = 15;
    }
    if (i == NN-1) offs[NN] = NE;
    // contention-free bucket counting: wave ballots -> block sums -> 16 atomics/block
    #pragma unroll
    for (int k = 0; k < 16; ++k){
        unsigned long long bal = __ballot(sv == k);
        if (lane == 0) wcnt[wv][k] = __popcll(bal);
    }
    __syncthreads();
    if (t < 16){
        int c = wcnt[0][t] + wcnt[1][t] + wcnt[2][t] + wcnt[3][t];
        if (c) atomicAdd(&bcnt[t], c);
    }
}

// ---------------- degree buckets: prefix + blocked scatter (perm) ----------------
__global__ void bpfx(const int* __restrict__ bcnt, int* __restrict__ bcur){
    if (threadIdx.x == 0){
        int run = 0;
        for (int k = 0; k < 16; ++k){ bcur[k] = run; run += bcnt[k]; }
    }
}
__global__ __launch_bounds__(256) void bscat(const int* __restrict__ hist, int* __restrict__ bcur,
                                             int* __restrict__ perm){
    __shared__ int wcnt[4][16];
    __shared__ int wpre[4][16];
    __shared__ int bbase[16];
    int t = threadIdx.x, d = blockIdx.x*256 + t;
    int lane = t & 63, wv = t >> 6;
    bool valid = (d < NN);
    int sv = 16;
    if (valid){ sv = (hist[d] + 15) >> 4; if (sv > 15) sv = 15; }
    int myrank = 0;
    unsigned long long lmask = (1ull << lane) - 1ull;
    #pragma unroll
    for (int k = 0; k < 16; ++k){
        unsigned long long bal = __ballot(sv == k);
        if (sv == k) myrank = __popcll(bal & lmask);
        if (lane == 0) wcnt[wv][k] = __popcll(bal);
    }
    __syncthreads();
    if (t < 16){
        int c0 = wcnt[0][t], c1 = wcnt[1][t], c2 = wcnt[2][t], c3 = wcnt[3][t];
        wpre[0][t] = 0; wpre[1][t] = c0; wpre[2][t] = c0+c1; wpre[3][t] = c0+c1+c2;
        int tot = c0+c1+c2+c3;
        bbase[t] = tot ? atomicAdd(&bcur[t], tot) : 0;
    }
    __syncthreads();
    if (valid) perm[bbase[sv] + wpre[wv][sv] + myrank] = d;
}

// ---------------- counting sort: payload = {meta, px, py, 0} (16B) ----------------
__global__ void scatter_k(const int* __restrict__ ei, const float* __restrict__ pseudo,
                          int* __restrict__ cursor, uint4* __restrict__ payA){
    int e = blockIdx.x*blockDim.x + threadIdx.x;
    if (e >= NE) return;
    float2 ps = *(const float2*)(pseudo + 2*(size_t)e);
    float px = ps.x * 4.0f, py = ps.y * 4.0f;
    int lx = min(max((int)floorf(px), 0), 3);
    int ly = min(max((int)floorf(py), 0), 3);
    uint meta = (uint)ei[e] | ((uint)lx<<16) | ((uint)ly<<18);   // src < 65536
    int pos = atomicAdd(&cursor[ei[NE + e]], 1);
    payA[pos] = make_uint4(meta, __float_as_uint(px), __float_as_uint(py), 0u);
}

// ---------------- pack [Wflat;root] into MFMA B-fragment layout, bf16 ----------------
template<int IN>
__global__ void wprep_k(const float* __restrict__ W, const float* __restrict__ root, ushort* __restrict__ Bp){
    const int total = 26*IN*64;
    int tid = blockIdx.x*blockDim.x + threadIdx.x;
    if (tid >= total) return;
    int j    = tid & 7;
    int lane = (tid >> 3) & 63;
    int ctkt = tid >> 9;
    int ct   = ctkt & 3;
    int kt   = ctkt >> 2;
    int kk   = kt*32 + (lane>>4)*8 + j;
    int col  = ct*16 + (lane & 15);
    float v;
    if (kk < 25*IN){ int k = kk / IN; int i = kk % IN; v = W[((size_t)k*IN + i)*64 + col]; }
    else           { v = root[(size_t)(kk - 25*IN)*64 + col]; }
    Bp[tid] = f2bf(v);
}

// ---------------- layer 1: CSR reduce, unroll-4 batched loads ----------------
__global__ __launch_bounds__(256) void reduce1_k(const float* __restrict__ x, const uint4* __restrict__ payA,
                                                 const int* __restrict__ offs, const float* __restrict__ invc,
                                                 const float* __restrict__ W1, const float* __restrict__ root1,
                                                 const float* __restrict__ b1, ushort* __restrict__ h1bf){
    __shared__ float w1s[25*32];
    for (int i = threadIdx.x; i < 25*32; i += 256) w1s[i] = W1[i];
    __syncthreads();
    int wid  = threadIdx.x >> 6;
    int lane = threadIdx.x & 63;
    int o    = lane & 31;
    int half = lane >> 5;
    int d    = blockIdx.x*4 + wid;
    int s = offs[d], e = offs[d+1];
    float acc = 0.f;
#define E1(QA, XS) { uint meta = (QA).x; \
    int lx = (meta>>16)&3, ly = (meta>>18)&3; \
    float px = __uint_as_float((QA).y), py = __uint_as_float((QA).z); \
    float fx = px - (float)lx, fy = py - (float)ly; \
    float gx = 1.f - fx, gy = 1.f - fy; \
    float wa = half ? fx*gy : gx*gy; \
    float wb = half ? fx*fy : gx*fy; \
    int ka = ly*5 + lx + half; \
    acc += (wa*w1s[ka*32 + o] + wb*w1s[(ka+5)*32 + o]) * (XS); }
    int p = s;
    for (; p + 4 <= e; p += 4){
        uint4 a0 = payA[p], a1 = payA[p+1], a2 = payA[p+2], a3 = payA[p+3];
        float x0 = x[a0.x & 0xFFFF], x1 = x[a1.x & 0xFFFF];
        float x2 = x[a2.x & 0xFFFF], x3 = x[a3.x & 0xFFFF];
        E1(a0, x0) E1(a1, x1) E1(a2, x2) E1(a3, x3)
    }
    for (; p < e; ++p){
        uint4 a0 = payA[p];
        float x0 = x[a0.x & 0xFFFF];
        E1(a0, x0)
    }
#undef E1
    acc += __shfl_xor(acc, 32);
    if (half == 0){
        float val = acc*invc[d] + x[d]*root1[o] + b1[o];
        val = val > 0.f ? val : expm1f(val);
        h1bf[(size_t)d*32 + o] = f2bf(val);
    }
}

// weight for spline row (i0,j0): closed-form saturated linear, round-to-nearest bf16
#define WCALC(Q0, AH) { \
    float px_ = __uint_as_float((Q0).y), py_ = __uint_as_float((Q0).z); \
    float wx_ = fmaxf(1.f - fabsf(px_ - fi0), 0.f); \
    float wy_ = fmaxf(1.f - fabsf(py_ - fj0), 0.f); \
    (AH) = (short)f2bf(wx_ * wy_); }

// async payload staging: global_load_lds 16B/lane (lanes 0..rem-1), PAD prefill for tail lanes
#define STAGE(BUF, STEP) { \
    int rem_ = h - (STEP)*16; if (rem_ > 16) rem_ = 16; \
    if (lane < 16 && lane >= rem_) eA[w][BUF][lane] = PAD4; \
    if (lane < rem_){ \
        __builtin_amdgcn_global_load_lds( \
            (const __attribute__((address_space(1))) void*)(payA + (size_t)s + (STEP)*16 + lane), \
            (__attribute__((address_space(3))) void*)&eA[w][BUF][lane], 16, 0, 0); \
    } }

// ---------------- fused layer IN=32: 16 bucketed nodes/block ----------------
template<int MODE>
__global__ __launch_bounds__(512) void fused32(
        const ushort* __restrict__ hin, const uint4* __restrict__ payA,
        const int* __restrict__ offs, const float* __restrict__ invc,
        const int* __restrict__ perm,
        const ushort* __restrict__ Bp, const float* __restrict__ bias,
        const int* __restrict__ batch, ushort* __restrict__ hout,
        float* __restrict__ pooled, int* __restrict__ gcnt)
{
    constexpr int KT = 26, KH = 13;
    __shared__ __align__(16) ushort Sb[KT*512];
    __shared__ __align__(16) uint4 eA[8][2][16];
    __shared__ float red[1024];
    __shared__ float outS[1024];
    __shared__ int pdS[16];

    const int tid = threadIdx.x, lane = tid & 63, w = tid >> 6;
    const int ln31 = lane & 31, kg2 = lane >> 5;
    const int d0 = blockIdx.x * 16;
    const float fi0 = (float)(ln31 % 5), fj0 = (float)(ln31 / 5);
    const uint4 PAD4 = make_uint4(0u, PADW, PADW, 0u);

    if (tid < 16) pdS[tid] = perm[d0 + tid];

    for (int nn = 0; nn < 2; ++nn){
        const int node = w*2 + nn;
        const int d = perm[d0 + node];
        int s = offs[d];
        int h = offs[d+1] - s;
        int steps = (h + 15) >> 4;

        f32x16 accH;
        #pragma unroll
        for (int q = 0; q < 16; ++q) accH[q] = 0.f;

        if (steps > 0) STAGE(0, 0)
        for (int ks = 0; ks < steps; ++ks){
            int cb = ks & 1;
            if (ks+1 < steps){
                STAGE(cb^1, ks+1)
                asm volatile("s_waitcnt vmcnt(1)" ::: "memory");
            } else {
                asm volatile("s_waitcnt vmcnt(0)" ::: "memory");
            }
            __builtin_amdgcn_sched_barrier(0);
            short8 ah; short8 bfv;
            #pragma unroll
            for (int j = 0; j < 8; ++j){
                uint4 q0 = eA[w][cb][kg2*8 + j];
                WCALC(q0, ah[j])
                bfv[j] = (short)hin[(size_t)(q0.x & 0xFFFFu)*32 + ln31];
            }
            accH = __builtin_amdgcn_mfma_f32_32x32x16_bf16(ah, bfv, accH, 0, 0, 0);
        }

        {
            float ic = invc[d];
            int jd  = ln31 & 7;
            int l3  = ln31 >> 3;
            #pragma unroll
            for (int reg = 0; reg < 16; ++reg){
                int r = (reg & 3) + 8*(reg >> 2) + 4*kg2;
                if (r < 25)
                    Sb[r*512 + iswz(l3*16 + node)*8 + jd] = f2bf(accH[reg]*ic);
            }
            if (lane < 32)
                Sb[25*512 + iswz(((lane>>3)&3)*16 + node)*8 + (lane&7)] = hin[(size_t)d*32 + lane];
        }
    }
    __syncthreads();

    {
        int ct = w & 3, kh = w >> 2;
        int c15 = lane & 15, kg = lane >> 4;
        int ig = iswz(lane);
        f32x4 a4 = {0.f,0.f,0.f,0.f};
        const ushort* bb = Bp + ct*512 + (size_t)lane*8;
        #pragma unroll
        for (int k = 0; k < KH; ++k){
            int kt = kh*KH + k;
            short8 a = *(const short8*)(Sb + kt*512 + ig*8);
            short8 b = *(const short8*)(bb + (size_t)kt*2048);
            a4 = __builtin_amdgcn_mfma_f32_16x16x32_bf16(a, b, a4, 0, 0, 0);
        }
        if (kh == 1){
            float* rr = red + (ct*64 + lane)*4;
            rr[0]=a4[0]; rr[1]=a4[1]; rr[2]=a4[2]; rr[3]=a4[3];
        }
        __syncthreads();
        if (kh == 0){
            const float* rr = red + (ct*64 + lane)*4;
            int col = ct*16 + c15;
            float bs = bias[col];
            #pragma unroll
            for (int jq = 0; jq < 4; ++jq){
                int r16 = kg*4 + jq;
                float v = a4[jq] + rr[jq] + bs;
                v = v > 0.f ? v : expm1f(v);
                if (MODE == 0) ((ushort*)outS)[r16*64 + col] = f2bf(v);
                else           outS[r16*64 + col] = v;
            }
        }
    }
    __syncthreads();

    if (MODE == 0){
        int row = tid >> 5, c2 = tid & 31;
        ((uint*)hout)[(size_t)pdS[row]*32 + c2] = ((const uint*)outS)[tid];
    } else {
        if (w == 0){
            #pragma unroll
            for (int r = 0; r < 16; ++r)
                atomicAdd(&pooled[batch[pdS[r]]*64 + lane], outS[r*64 + lane]);
        } else if (w == 1 && lane < 16){
            atomicAdd(&gcnt[batch[pdS[lane]]], 1);
        }
    }
}

// ---------------- fused layer IN=64: 16 bucketed nodes/block + paired features ----------------
template<int MODE>
__global__ __launch_bounds__(512) void fused64(
        const ushort* __restrict__ hin, const uint4* __restrict__ payA,
        const int* __restrict__ offs, const float* __restrict__ invc,
        const int* __restrict__ perm,
        const ushort* __restrict__ Bp, const float* __restrict__ bias,
        const int* __restrict__ batch, ushort* __restrict__ hout,
        float* __restrict__ pooled, int* __restrict__ gcnt)
{
    constexpr int KT = 52, KH = 26;
    __shared__ __align__(16) ushort Sb[KT*512];
    __shared__ __align__(16) uint4 eA[8][2][16];
    __shared__ float red[1024];
    __shared__ float outS[1024];
    __shared__ int pdS[16];

    const int tid = threadIdx.x, lane = tid & 63, w = tid >> 6;
    const int ln31 = lane & 31, kg2 = lane >> 5;
    const int d0 = blockIdx.x * 16;
    const float fi0 = (float)(ln31 % 5), fj0 = (float)(ln31 / 5);
    const uint4 PAD4 = make_uint4(0u, PADW, PADW, 0u);

    if (tid < 16) pdS[tid] = perm[d0 + tid];

    for (int nn = 0; nn < 2; ++nn){
        const int node = w*2 + nn;
        const int d = perm[d0 + node];
        int s = offs[d];
        int h = offs[d+1] - s;
        int steps = (h + 15) >> 4;

        f32x16 acc0, acc1;
        #pragma unroll
        for (int q = 0; q < 16; ++q){ acc0[q] = 0.f; acc1[q] = 0.f; }

        if (steps > 0) STAGE(0, 0)
        for (int ks = 0; ks < steps; ++ks){
            int cb = ks & 1;
            if (ks+1 < steps){
                STAGE(cb^1, ks+1)
                asm volatile("s_waitcnt vmcnt(1)" ::: "memory");
            } else {
                asm volatile("s_waitcnt vmcnt(0)" ::: "memory");
            }
            __builtin_amdgcn_sched_barrier(0);
            short8 ah; uint hx[8];
            #pragma unroll
            for (int j = 0; j < 8; ++j){
                uint4 q0 = eA[w][cb][kg2*8 + j];
                WCALC(q0, ah[j])
                hx[j] = *(const uint*)(hin + (size_t)(q0.x & 0xFFFFu)*64 + 2*ln31);
            }
            short8 b0, b1;
            #pragma unroll
            for (int j = 0; j < 8; ++j){
                b0[j] = (short)(ushort)hx[j];
                b1[j] = (short)(ushort)(hx[j] >> 16);
            }
            acc0 = __builtin_amdgcn_mfma_f32_32x32x16_bf16(ah, b0, acc0, 0, 0, 0);
            acc1 = __builtin_amdgcn_mfma_f32_32x32x16_bf16(ah, b1, acc1, 0, 0, 0);
        }

        // deposit: acc0/acc1 hold S[r][2*ln31] / S[r][2*ln31+1]
        {
            float ic = invc[d];
            int off0 = 2*ln31;
            int fhi  = ln31 >> 4;
            int kgp  = (off0 >> 3) & 3;
            int jd0  = off0 & 7;
            int gsl  = iswz(kgp*16 + node)*8;
            #pragma unroll
            for (int reg = 0; reg < 16; ++reg){
                int r = (reg & 3) + 8*(reg >> 2) + 4*kg2;
                if (r < 25){
                    int kt = r*2 + fhi;
                    uint pk = (uint)f2bf(acc0[reg]*ic) | ((uint)f2bf(acc1[reg]*ic) << 16);
                    *(uint*)(Sb + kt*512 + gsl + jd0) = pk;
                }
            }
            int f = lane;
            Sb[(50 + (f>>5))*512 + iswz(((f>>3)&3)*16 + node)*8 + (f&7)] = hin[(size_t)d*64 + f];
        }
    }
    __syncthreads();

    // node-GEMM: 8 waves = 4 col-tiles x 2 K-halves, M=16
    {
        int ct = w & 3, kh = w >> 2;
        int c15 = lane & 15, kg = lane >> 4;
        int ig = iswz(lane);
        f32x4 a4 = {0.f,0.f,0.f,0.f};
        const ushort* bb = Bp + ct*512 + (size_t)lane*8;
        #pragma unroll
        for (int k = 0; k < KH; ++k){
            int kt = kh*KH + k;
            short8 a = *(const short8*)(Sb + kt*512 + ig*8);
            short8 b = *(const short8*)(bb + (size_t)kt*2048);
            a4 = __builtin_amdgcn_mfma_f32_16x16x32_bf16(a, b, a4, 0, 0, 0);
        }
        if (kh == 1){
            float* rr = red + (ct*64 + lane)*4;
            rr[0]=a4[0]; rr[1]=a4[1]; rr[2]=a4[2]; rr[3]=a4[3];
        }
        __syncthreads();
        if (kh == 0){
            const float* rr = red + (ct*64 + lane)*4;
            int col = ct*16 + c15;
            float bs = bias[col];
            #pragma unroll
            for (int jq = 0; jq < 4; ++jq){
                int r16 = kg*4 + jq;
                float v = a4[jq] + rr[jq] + bs;
                v = v > 0.f ? v : expm1f(v);
                if (MODE == 0) ((ushort*)outS)[r16*64 + col] = f2bf(v);
                else           outS[r16*64 + col] = v;
            }
        }
    }
    __syncthreads();

    // ---- output ----
    if (MODE == 0){
        int row = tid >> 5, c2 = tid & 31;
        ((uint*)hout)[(size_t)pdS[row]*32 + c2] = ((const uint*)outS)[tid];
    } else {
        if (w == 0){
            #pragma unroll
            for (int r = 0; r < 16; ++r)
                atomicAdd(&pooled[batch[pdS[r]]*64 + lane], outS[r*64 + lane]);
        } else if (w == 1 && lane < 16){
            atomicAdd(&gcnt[batch[pdS[lane]]], 1);
        }
    }
}

// ---------------- head: graph mean-pool -> fc -> log_softmax ----------------
__global__ __launch_bounds__(128) void head_k(const float* __restrict__ pooled, const int* __restrict__ gcnt,
                                              const float* __restrict__ fcw, const float* __restrict__ fcb,
                                              float* __restrict__ out){
    int g = threadIdx.x;
    if (g >= NG) return;
    float inv = 1.0f / fmaxf((float)gcnt[g], 1.0f);
    float logits[10];
    #pragma unroll
    for (int c = 0; c < 10; ++c) logits[c] = fcb[c];
    for (int o = 0; o < 64; ++o){
        float m = pooled[g*64 + o] * inv;
        #pragma unroll
        for (int c = 0; c < 10; ++c) logits[c] += m * fcw[o*10 + c];
    }
    float mx = logits[0];
    #pragma unroll
    for (int c = 1; c < 10; ++c) mx = fmaxf(mx, logits[c]);
    float ssum = 0.f;
    #pragma unroll
    for (int c = 0; c < 10; ++c) ssum += expf(logits[c] - mx);
    float lse = logf(ssum) + mx;
    #pragma unroll
    for (int c = 0; c < 10; ++c) out[g*10 + c] = logits[c] - lse;
}

extern "C" void kernel_launch(void* const* d_in, const int* in_sizes, int n_in,
                              void* d_out, int out_size, void* d_ws, size_t ws_size,
                              hipStream_t stream) {
    const float* x      = (const float*)d_in[0];
    const float* pseudo = (const float*)d_in[2];
    const int*   ei     = (const int*)  d_in[3];
    const int*   batch  = (const int*)  d_in[4];
    const float* W1     = (const float*)d_in[5];
    const float* root1  = (const float*)d_in[6];
    const float* b1     = (const float*)d_in[7];
    const float* W2     = (const float*)d_in[8];
    const float* root2  = (const float*)d_in[9];
    const float* b2     = (const float*)d_in[10];
    const float* W3     = (const float*)d_in[11];
    const float* root3  = (const float*)d_in[12];
    const float* b3     = (const float*)d_in[13];
    const float* fcw    = (const float*)d_in[14];
    const float* fcb    = (const float*)d_in[15];
    float* out = (float*)d_out;

    char* ws = (char*)d_ws;
    size_t off = 0;
    auto alloc = [&](size_t bytes)->char*{ char* p = ws + off; off += (bytes + 255) / 256 * 256; return p; };
    uint4*  payA   = (uint4*) alloc((size_t)NE*16);
    ushort* h1bf   = (ushort*)alloc((size_t)NN*32*2);
    ushort* h2bf   = (ushort*)alloc((size_t)NN*64*2);
    int*    hist   = (int*)   alloc((size_t)NN*4);
    int*    offs   = (int*)   alloc((size_t)(NN+1)*4);
    int*    cursor = (int*)   alloc((size_t)NN*4);
    float*  invc   = (float*) alloc((size_t)NN*4);
    int*    bsum   = (int*)   alloc((size_t)NB_SCAN*4);
    int*    bpre   = (int*)   alloc((size_t)NB_SCAN*4);
    int*    bcnt   = (int*)   alloc((size_t)16*4);
    int*    bcur   = (int*)   alloc((size_t)16*4);
    int*    perm   = (int*)   alloc((size_t)NN*4);
    ushort* Bp2    = (ushort*)alloc((size_t)26*2048*2);
    ushort* Bp3    = (ushort*)alloc((size_t)52*2048*2);
    float*  pooled = (float*) alloc((size_t)NG*64*4);
    int*    gcnt   = (int*)   alloc((size_t)NG*4);
    (void)ws_size; (void)in_sizes; (void)n_in; (void)out_size;

    zero_k   <<<NB_SCAN, 256, 0, stream>>>(hist, pooled, gcnt, bcnt);
    hist_k   <<<(NE+255)/256, 256, 0, stream>>>(ei, hist);
    scan1    <<<NB_SCAN, 256, 0, stream>>>(hist, bsum);
    scan2    <<<1, 256, 0, stream>>>(bsum, bpre);
    scan3    <<<NB_SCAN, 256, 0, stream>>>(hist, bpre, offs, cursor, invc, bcnt);
    bpfx     <<<1, 64, 0, stream>>>(bcnt, bcur);
    bscat    <<<NB_SCAN, 256, 0, stream>>>(hist, bcur, perm);
    scatter_k<<<(NE+255)/256, 256, 0, stream>>>(ei, pseudo, cursor, payA);
    wprep_k<32><<<(26*32*64 + 255)/256, 256, 0, stream>>>(W2, root2, Bp2);
    wprep_k<64><<<(26*64*64 + 255)/256, 256, 0, stream>>>(W3, root3, Bp3);
    reduce1_k<<<NN/4, 256, 0, stream>>>(x, payA, offs, invc, W1, root1, b1, h1bf);
    fused32<0><<<NN/16, 512, 0, stream>>>(h1bf, payA, offs, invc, perm, Bp2, b2, batch, h2bf, pooled, gcnt);
    fused64<1><<<NN/16, 512, 0, stream>>>(h2bf, payA, offs, invc, perm, Bp3, b3, batch, h2bf, pooled, gcnt);
    head_k   <<<1, 128, 0, stream>>>(pooled, gcnt, fcw, fcb, out);
}

// Round 23
// 275.551 us; speedup vs baseline: 3.9697x; 1.2744x over previous
//
#include <hip/hip_runtime.h>

#define NN 50000
#define NE 800000
#define NG 128
#define NB_SCAN 196        // ceil(NN/256)
#define PADW 0xC1000000u   // bits of -8.0f : pad coords -> weight exactly 0

typedef unsigned int uint;
typedef unsigned short ushort;
typedef __attribute__((ext_vector_type(8))) short short8;
typedef __attribute__((ext_vector_type(4))) float f32x4;
typedef __attribute__((ext_vector_type(16))) float f32x16;

__device__ __forceinline__ float bf2f(ushort u){ union{uint i; float f;} v; v.i=(uint)u<<16; return v.f; }
__device__ __forceinline__ ushort f2bf(float f){ union{float f; uint i;} v; v.f=f; return (ushort)((v.i + 0x7FFFu + ((v.i>>16)&1u))>>16); }
__device__ __forceinline__ int iswz(int i){ return i ^ ((i>>4)&3); }   // granule swizzle, involution

// ---------------- zero scratch re-initialized every call ----------------
__global__ void zero_k(int* hist, float* pooled, int* gcnt){
    int i = blockIdx.x*blockDim.x + threadIdx.x;
    if (i < NN) hist[i] = 0;
    if (i < NG*64) pooled[i] = 0.f;
    if (i < NG) gcnt[i] = 0;
}

// ---------------- dst histogram ----------------
__global__ void hist_k(const int* __restrict__ ei, int* __restrict__ hist){
    int e = blockIdx.x*blockDim.x + threadIdx.x;
    if (e < NE) atomicAdd(&hist[ei[NE + e]], 1);
}

// ---------------- hierarchical exclusive scan ----------------
__global__ __launch_bounds__(256) void scan1(const int* __restrict__ hist, int* __restrict__ bsum){
    __shared__ int sm[256];
    int t = threadIdx.x, i = blockIdx.x*256 + t;
    sm[t] = (i < NN) ? hist[i] : 0;
    __syncthreads();
    for (int o = 128; o > 0; o >>= 1){ if (t < o) sm[t] += sm[t+o]; __syncthreads(); }
    if (t == 0) bsum[blockIdx.x] = sm[0];
}
__global__ __launch_bounds__(256) void scan2(const int* __restrict__ bsum, int* __restrict__ bpre){
    __shared__ int sm[256];
    int t = threadIdx.x;
    int v = (t < NB_SCAN) ? bsum[t] : 0;
    sm[t] = v; __syncthreads();
    int acc = v;
    for (int o = 1; o < 256; o <<= 1){
        int u = (t >= o) ? sm[t-o] : 0; __syncthreads();
        acc += u; sm[t] = acc; __syncthreads();
    }
    if (t < NB_SCAN) bpre[t] = acc - v;
}
__global__ __launch_bounds__(256) void scan3(const int* __restrict__ hist, const int* __restrict__ bpre,
                                             int* __restrict__ offs, int* __restrict__ cursor,
                                             float* __restrict__ invc){
    __shared__ int sm[256];
    int t = threadIdx.x, b = blockIdx.x, i = b*256 + t;
    int v = (i < NN) ? hist[i] : 0;
    sm[t] = v; __syncthreads();
    int acc = v;
    for (int o = 1; o < 256; o <<= 1){
        int u = (t >= o) ? sm[t-o] : 0; __syncthreads();
        acc += u; sm[t] = acc; __syncthreads();
    }
    int excl = acc - v + bpre[b];
    if (i < NN){ offs[i] = excl; cursor[i] = excl; invc[i] = 1.0f/(float)max(v,1); }
    if (i == NN-1) offs[NN] = NE;
}

// ---------------- counting sort: payload = {meta, px, py, 0} (16B) ----------------
__global__ void scatter_k(const int* __restrict__ ei, const float* __restrict__ pseudo,
                          int* __restrict__ cursor, uint4* __restrict__ payA){
    int e = blockIdx.x*blockDim.x + threadIdx.x;
    if (e >= NE) return;
    float2 ps = *(const float2*)(pseudo + 2*(size_t)e);
    float px = ps.x * 4.0f, py = ps.y * 4.0f;
    int lx = min(max((int)floorf(px), 0), 3);
    int ly = min(max((int)floorf(py), 0), 3);
    uint meta = (uint)ei[e] | ((uint)lx<<16) | ((uint)ly<<18);   // src < 65536
    int pos = atomicAdd(&cursor[ei[NE + e]], 1);
    payA[pos] = make_uint4(meta, __float_as_uint(px), __float_as_uint(py), 0u);
}

// ---------------- pack [Wflat;root] into MFMA B-fragment layout, bf16 ----------------
template<int IN>
__global__ void wprep_k(const float* __restrict__ W, const float* __restrict__ root, ushort* __restrict__ Bp){
    const int total = 26*IN*64;
    int tid = blockIdx.x*blockDim.x + threadIdx.x;
    if (tid >= total) return;
    int j    = tid & 7;
    int lane = (tid >> 3) & 63;
    int ctkt = tid >> 9;
    int ct   = ctkt & 3;
    int kt   = ctkt >> 2;
    int kk   = kt*32 + (lane>>4)*8 + j;
    int col  = ct*16 + (lane & 15);
    float v;
    if (kk < 25*IN){ int k = kk / IN; int i = kk % IN; v = W[((size_t)k*IN + i)*64 + col]; }
    else           { v = root[(size_t)(kk - 25*IN)*64 + col]; }
    Bp[tid] = f2bf(v);
}

// ---------------- layer 1: CSR reduce, unroll-4 batched loads ----------------
__global__ __launch_bounds__(256) void reduce1_k(const float* __restrict__ x, const uint4* __restrict__ payA,
                                                 const int* __restrict__ offs, const float* __restrict__ invc,
                                                 const float* __restrict__ W1, const float* __restrict__ root1,
                                                 const float* __restrict__ b1, ushort* __restrict__ h1bf){
    __shared__ float w1s[25*32];
    for (int i = threadIdx.x; i < 25*32; i += 256) w1s[i] = W1[i];
    __syncthreads();
    int wid  = threadIdx.x >> 6;
    int lane = threadIdx.x & 63;
    int o    = lane & 31;
    int half = lane >> 5;
    int d    = blockIdx.x*4 + wid;
    int s = offs[d], e = offs[d+1];
    float acc = 0.f;
#define E1(QA, XS) { uint meta = (QA).x; \
    int lx = (meta>>16)&3, ly = (meta>>18)&3; \
    float px = __uint_as_float((QA).y), py = __uint_as_float((QA).z); \
    float fx = px - (float)lx, fy = py - (float)ly; \
    float gx = 1.f - fx, gy = 1.f - fy; \
    float wa = half ? fx*gy : gx*gy; \
    float wb = half ? fx*fy : gx*fy; \
    int ka = ly*5 + lx + half; \
    acc += (wa*w1s[ka*32 + o] + wb*w1s[(ka+5)*32 + o]) * (XS); }
    int p = s;
    for (; p + 4 <= e; p += 4){
        uint4 a0 = payA[p], a1 = payA[p+1], a2 = payA[p+2], a3 = payA[p+3];
        float x0 = x[a0.x & 0xFFFF], x1 = x[a1.x & 0xFFFF];
        float x2 = x[a2.x & 0xFFFF], x3 = x[a3.x & 0xFFFF];
        E1(a0, x0) E1(a1, x1) E1(a2, x2) E1(a3, x3)
    }
    for (; p < e; ++p){
        uint4 a0 = payA[p];
        float x0 = x[a0.x & 0xFFFF];
        E1(a0, x0)
    }
#undef E1
    acc += __shfl_xor(acc, 32);
    if (half == 0){
        float val = acc*invc[d] + x[d]*root1[o] + b1[o];
        val = val > 0.f ? val : expm1f(val);
        h1bf[(size_t)d*32 + o] = f2bf(val);
    }
}

// weight for spline row (i0,j0) from coords: closed-form saturated linear; hi/lo bf16 by truncation
#define WCALC(Q0, AH, AL) { \
    float px_ = __uint_as_float((Q0).y), py_ = __uint_as_float((Q0).z); \
    float wx_ = fmaxf(1.f - fabsf(px_ - fi0), 0.f); \
    float wy_ = fmaxf(1.f - fabsf(py_ - fj0), 0.f); \
    float wv_ = wx_ * wy_; \
    uint wb_ = __float_as_uint(wv_); \
    (AH) = (short)(ushort)(wb_ >> 16); \
    float hif_ = __uint_as_float(wb_ & 0xFFFF0000u); \
    (AL) = (short)(ushort)(__float_as_uint(wv_ - hif_) >> 16); }

// async payload staging: global_load_lds 16B/lane (lanes 0..rem-1), PAD prefill for tail lanes
#define STAGE(BUF, STEP) { \
    int rem_ = h - (STEP)*16; if (rem_ > 16) rem_ = 16; \
    if (lane < 16 && lane >= rem_) eA[w][BUF][lane] = PAD4; \
    if (lane < rem_){ \
        __builtin_amdgcn_global_load_lds( \
            (const __attribute__((address_space(1))) void*)(payA + (size_t)s + (STEP)*16 + lane), \
            (__attribute__((address_space(3))) void*)&eA[w][BUF][lane], 16, 0, 0); \
    } }

// ---------------- fused layer IN=32: 16 nodes/block, async-DMA double-buffered staging ----------------
template<int MODE>
__global__ __launch_bounds__(512) void fused32(
        const ushort* __restrict__ hin, const uint4* __restrict__ payA,
        const int* __restrict__ offs, const float* __restrict__ invc,
        const ushort* __restrict__ Bp, const float* __restrict__ bias,
        const int* __restrict__ batch, ushort* __restrict__ hout,
        float* __restrict__ pooled, int* __restrict__ gcnt)
{
    constexpr int KT = 26, KH = 13;
    __shared__ __align__(16) ushort Sb[KT*512];
    __shared__ __align__(16) uint4 eA[8][2][16];
    __shared__ float red[1024];
    __shared__ float outS[1024];

    const int tid = threadIdx.x, lane = tid & 63, w = tid >> 6;
    const int ln31 = lane & 31, kg2 = lane >> 5;
    const int d0 = blockIdx.x * 16;
    const float fi0 = (float)(ln31 % 5), fj0 = (float)(ln31 / 5);
    const uint4 PAD4 = make_uint4(0u, PADW, PADW, 0u);

    for (int nn = 0; nn < 2; ++nn){
        const int node = w*2 + nn;
        const int d = d0 + node;
        int s = offs[d];
        int h = offs[d+1] - s;
        int steps = (h + 15) >> 4;

        f32x16 accH;
        #pragma unroll
        for (int q = 0; q < 16; ++q) accH[q] = 0.f;

        if (steps > 0) STAGE(0, 0)
        for (int ks = 0; ks < steps; ++ks){
            int cb = ks & 1;
            if (ks+1 < steps){
                STAGE(cb^1, ks+1)
                asm volatile("s_waitcnt vmcnt(1)" ::: "memory");
            } else {
                asm volatile("s_waitcnt vmcnt(0)" ::: "memory");
            }
            __builtin_amdgcn_sched_barrier(0);
            short8 ah, al; short8 bfv;
            #pragma unroll
            for (int j = 0; j < 8; ++j){
                uint4 q0 = eA[w][cb][kg2*8 + j];
                WCALC(q0, ah[j], al[j])
                bfv[j] = (short)hin[(size_t)(q0.x & 0xFFFFu)*32 + ln31];
            }
            accH = __builtin_amdgcn_mfma_f32_32x32x16_bf16(ah, bfv, accH, 0, 0, 0);
            accH = __builtin_amdgcn_mfma_f32_32x32x16_bf16(al, bfv, accH, 0, 0, 0);
        }

        {
            float ic = invc[d];
            int jd  = ln31 & 7;
            int l3  = ln31 >> 3;
            #pragma unroll
            for (int reg = 0; reg < 16; ++reg){
                int r = (reg & 3) + 8*(reg >> 2) + 4*kg2;
                if (r < 25)
                    Sb[r*512 + iswz(l3*16 + node)*8 + jd] = f2bf(accH[reg]*ic);
            }
            if (lane < 32)
                Sb[25*512 + iswz(((lane>>3)&3)*16 + node)*8 + (lane&7)] = hin[(size_t)d*32 + lane];
        }
    }
    __syncthreads();

    {
        int ct = w & 3, kh = w >> 2;
        int c15 = lane & 15, kg = lane >> 4;
        int ig = iswz(lane);
        f32x4 a4 = {0.f,0.f,0.f,0.f};
        const ushort* bb = Bp + ct*512 + (size_t)lane*8;
        #pragma unroll
        for (int k = 0; k < KH; ++k){
            int kt = kh*KH + k;
            short8 a = *(const short8*)(Sb + kt*512 + ig*8);
            short8 b = *(const short8*)(bb + (size_t)kt*2048);
            a4 = __builtin_amdgcn_mfma_f32_16x16x32_bf16(a, b, a4, 0, 0, 0);
        }
        if (kh == 1){
            float* rr = red + (ct*64 + lane)*4;
            rr[0]=a4[0]; rr[1]=a4[1]; rr[2]=a4[2]; rr[3]=a4[3];
        }
        __syncthreads();
        if (kh == 0){
            const float* rr = red + (ct*64 + lane)*4;
            int col = ct*16 + c15;
            float bs = bias[col];
            #pragma unroll
            for (int jq = 0; jq < 4; ++jq){
                int r16 = kg*4 + jq;
                float v = a4[jq] + rr[jq] + bs;
                v = v > 0.f ? v : expm1f(v);
                if (MODE == 0) ((ushort*)outS)[r16*64 + col] = f2bf(v);
                else           outS[r16*64 + col] = v;
            }
        }
    }
    __syncthreads();

    if (MODE == 0){
        uint* dst = (uint*)(hout + (size_t)d0*64);
        dst[tid] = ((const uint*)outS)[tid];
    } else {
        if (w == 0){
            int c = lane;
            float run = 0.f; int gprev = batch[d0];
            for (int r = 0; r < 16; ++r){
                int g = batch[d0 + r];
                if (g != gprev){ atomicAdd(&pooled[gprev*64 + c], run); run = 0.f; gprev = g; }
                run += outS[r*64 + c];
            }
            atomicAdd(&pooled[gprev*64 + c], run);
        } else if (w == 1 && lane == 0){
            int cnt = 0; int gprev = batch[d0];
            for (int r = 0; r < 16; ++r){
                int g = batch[d0 + r];
                if (g != gprev){ atomicAdd(&gcnt[gprev], cnt); cnt = 0; gprev = g; }
                cnt++;
            }
            atomicAdd(&gcnt[gprev], cnt);
        }
    }
}

// ---------------- fused layer IN=64: async-DMA staging + paired-feature permutation ----------------
template<int MODE>
__global__ __launch_bounds__(512) void fused64(
        const ushort* __restrict__ hin, const uint4* __restrict__ payA,
        const int* __restrict__ offs, const float* __restrict__ invc,
        const ushort* __restrict__ Bp, const float* __restrict__ bias,
        const int* __restrict__ batch, ushort* __restrict__ hout,
        float* __restrict__ pooled, int* __restrict__ gcnt)
{
    constexpr int KT = 52, KH = 26;
    __shared__ __align__(16) ushort Sb[KT*512];
    __shared__ __align__(16) uint4 eA[8][2][16];
    __shared__ float red[1024];
    __shared__ float outS[1024];

    const int tid = threadIdx.x, lane = tid & 63, w = tid >> 6;
    const int ln31 = lane & 31, kg2 = lane >> 5;
    const int d0 = blockIdx.x * 16;
    const float fi0 = (float)(ln31 % 5), fj0 = (float)(ln31 / 5);
    const uint4 PAD4 = make_uint4(0u, PADW, PADW, 0u);

    for (int nn = 0; nn < 2; ++nn){
        const int node = w*2 + nn;
        const int d = d0 + node;
        int s = offs[d];
        int h = offs[d+1] - s;
        int steps = (h + 15) >> 4;

        f32x16 acc0, acc1;
        #pragma unroll
        for (int q = 0; q < 16; ++q){ acc0[q] = 0.f; acc1[q] = 0.f; }

        if (steps > 0) STAGE(0, 0)
        for (int ks = 0; ks < steps; ++ks){
            int cb = ks & 1;
            if (ks+1 < steps){
                STAGE(cb^1, ks+1)
                asm volatile("s_waitcnt vmcnt(1)" ::: "memory");
            } else {
                asm volatile("s_waitcnt vmcnt(0)" ::: "memory");
            }
            __builtin_amdgcn_sched_barrier(0);
            short8 ah, al; uint hx[8];
            #pragma unroll
            for (int j = 0; j < 8; ++j){
                uint4 q0 = eA[w][cb][kg2*8 + j];
                WCALC(q0, ah[j], al[j])
                hx[j] = *(const uint*)(hin + (size_t)(q0.x & 0xFFFFu)*64 + 2*ln31);
            }
            short8 b0, b1;
            #pragma unroll
            for (int j = 0; j < 8; ++j){
                b0[j] = (short)(ushort)hx[j];
                b1[j] = (short)(ushort)(hx[j] >> 16);
            }
            acc0 = __builtin_amdgcn_mfma_f32_32x32x16_bf16(ah, b0, acc0, 0, 0, 0);
            acc0 = __builtin_amdgcn_mfma_f32_32x32x16_bf16(al, b0, acc0, 0, 0, 0);
            acc1 = __builtin_amdgcn_mfma_f32_32x32x16_bf16(ah, b1, acc1, 0, 0, 0);
            acc1 = __builtin_amdgcn_mfma_f32_32x32x16_bf16(al, b1, acc1, 0, 0, 0);
        }

        // deposit: acc0/acc1 hold S[r][2*ln31] / S[r][2*ln31+1]
        {
            float ic = invc[d];
            int off0 = 2*ln31;
            int fhi  = ln31 >> 4;
            int kgp  = (off0 >> 3) & 3;
            int jd0  = off0 & 7;
            int gsl  = iswz(kgp*16 + node)*8;
            #pragma unroll
            for (int reg = 0; reg < 16; ++reg){
                int r = (reg & 3) + 8*(reg >> 2) + 4*kg2;
                if (r < 25){
                    int kt = r*2 + fhi;
                    uint pk = (uint)f2bf(acc0[reg]*ic) | ((uint)f2bf(acc1[reg]*ic) << 16);
                    *(uint*)(Sb + kt*512 + gsl + jd0) = pk;
                }
            }
            int f = lane;
            Sb[(50 + (f>>5))*512 + iswz(((f>>3)&3)*16 + node)*8 + (f&7)] = hin[(size_t)d*64 + f];
        }
    }
    __syncthreads();

    // node-GEMM: 8 waves = 4 col-tiles x 2 K-halves, M=16
    {
        int ct = w & 3, kh = w >> 2;
        int c15 = lane & 15, kg = lane >> 4;
        int ig = iswz(lane);
        f32x4 a4 = {0.f,0.f,0.f,0.f};
        const ushort* bb = Bp + ct*512 + (size_t)lane*8;
        #pragma unroll
        for (int k = 0; k < KH; ++k){
            int kt = kh*KH + k;
            short8 a = *(const short8*)(Sb + kt*512 + ig*8);
            short8 b = *(const short8*)(bb + (size_t)kt*2048);
            a4 = __builtin_amdgcn_mfma_f32_16x16x32_bf16(a, b, a4, 0, 0, 0);
        }
        if (kh == 1){
            float* rr = red + (ct*64 + lane)*4;
            rr[0]=a4[0]; rr[1]=a4[1]; rr[2]=a4[2]; rr[3]=a4[3];
        }
        __syncthreads();
        if (kh == 0){
            const float* rr = red + (ct*64 + lane)*4;
            int col = ct*16 + c15;
            float bs = bias[col];
            #pragma unroll
            for (int jq = 0; jq < 4; ++jq){
                int r16 = kg*4 + jq;
                float v = a4[jq] + rr[jq] + bs;
                v = v > 0.f ? v : expm1f(v);
                if (MODE == 0) ((ushort*)outS)[r16*64 + col] = f2bf(v);
                else           outS[r16*64 + col] = v;
            }
        }
    }
    __syncthreads();

    // ---- output ----
    if (MODE == 0){
        uint* dst = (uint*)(hout + (size_t)d0*64);
        dst[tid] = ((const uint*)outS)[tid];
    } else {
        if (w == 0){
            int c = lane;
            float run = 0.f; int gprev = batch[d0];
            for (int r = 0; r < 16; ++r){
                int g = batch[d0 + r];
                if (g != gprev){ atomicAdd(&pooled[gprev*64 + c], run); run = 0.f; gprev = g; }
                run += outS[r*64 + c];
            }
            atomicAdd(&pooled[gprev*64 + c], run);
        } else if (w == 1 && lane == 0){
            int cnt = 0; int gprev = batch[d0];
            for (int r = 0; r < 16; ++r){
                int g = batch[d0 + r];
                if (g != gprev){ atomicAdd(&gcnt[gprev], cnt); cnt = 0; gprev = g; }
                cnt++;
            }
            atomicAdd(&gcnt[gprev], cnt);
        }
    }
}

// ---------------- head: graph mean-pool -> fc -> log_softmax ----------------
__global__ __launch_bounds__(128) void head_k(const float* __restrict__ pooled, const int* __restrict__ gcnt,
                                              const float* __restrict__ fcw, const float* __restrict__ fcb,
                                              float* __restrict__ out){
    int g = threadIdx.x;
    if (g >= NG) return;
    float inv = 1.0f / fmaxf((float)gcnt[g], 1.0f);
    float logits[10];
    #pragma unroll
    for (int c = 0; c < 10; ++c) logits[c] = fcb[c];
    for (int o = 0; o < 64; ++o){
        float m = pooled[g*64 + o] * inv;
        #pragma unroll
        for (int c = 0; c < 10; ++c) logits[c] += m * fcw[o*10 + c];
    }
    float mx = logits[0];
    #pragma unroll
    for (int c = 1; c < 10; ++c) mx = fmaxf(mx, logits[c]);
    float ssum = 0.f;
    #pragma unroll
    for (int c = 0; c < 10; ++c) ssum += expf(logits[c] - mx);
    float lse = logf(ssum) + mx;
    #pragma unroll
    for (int c = 0; c < 10; ++c) out[g*10 + c] = logits[c] - lse;
}

extern "C" void kernel_launch(void* const* d_in, const int* in_sizes, int n_in,
                              void* d_out, int out_size, void* d_ws, size_t ws_size,
                              hipStream_t stream) {
    const float* x      = (const float*)d_in[0];
    const float* pseudo = (const float*)d_in[2];
    const int*   ei     = (const int*)  d_in[3];
    const int*   batch  = (const int*)  d_in[4];
    const float* W1     = (const float*)d_in[5];
    const float* root1  = (const float*)d_in[6];
    const float* b1     = (const float*)d_in[7];
    const float* W2     = (const float*)d_in[8];
    const float* root2  = (const float*)d_in[9];
    const float* b2     = (const float*)d_in[10];
    const float* W3     = (const float*)d_in[11];
    const float* root3  = (const float*)d_in[12];
    const float* b3     = (const float*)d_in[13];
    const float* fcw    = (const float*)d_in[14];
    const float* fcb    = (const float*)d_in[15];
    float* out = (float*)d_out;

    char* ws = (char*)d_ws;
    size_t off = 0;
    auto alloc = [&](size_t bytes)->char*{ char* p = ws + off; off += (bytes + 255) / 256 * 256; return p; };
    uint4*  payA   = (uint4*) alloc((size_t)NE*16);
    ushort* h1bf   = (ushort*)alloc((size_t)NN*32*2);
    ushort* h2bf   = (ushort*)alloc((size_t)NN*64*2);
    int*    hist   = (int*)   alloc((size_t)NN*4);
    int*    offs   = (int*)   alloc((size_t)(NN+1)*4);
    int*    cursor = (int*)   alloc((size_t)NN*4);
    float*  invc   = (float*) alloc((size_t)NN*4);
    int*    bsum   = (int*)   alloc((size_t)NB_SCAN*4);
    int*    bpre   = (int*)   alloc((size_t)NB_SCAN*4);
    ushort* Bp2    = (ushort*)alloc((size_t)26*2048*2);
    ushort* Bp3    = (ushort*)alloc((size_t)52*2048*2);
    float*  pooled = (float*) alloc((size_t)NG*64*4);
    int*    gcnt   = (int*)   alloc((size_t)NG*4);
    (void)ws_size; (void)in_sizes; (void)n_in; (void)out_size;

    zero_k   <<<NB_SCAN, 256, 0, stream>>>(hist, pooled, gcnt);
    hist_k   <<<(NE+255)/256, 256, 0, stream>>>(ei, hist);
    scan1    <<<NB_SCAN, 256, 0, stream>>>(hist, bsum);
    scan2    <<<1, 256, 0, stream>>>(bsum, bpre);
    scan3    <<<NB_SCAN, 256, 0, stream>>>(hist, bpre, offs, cursor, invc);
    scatter_k<<<(NE+255)/256, 256, 0, stream>>>(ei, pseudo, cursor, payA);
    wprep_k<32><<<(26*32*64 + 255)/256, 256, 0, stream>>>(W2, root2, Bp2);
    wprep_k<64><<<(26*64*64 + 255)/256, 256, 0, stream>>>(W3, root3, Bp3);
    reduce1_k<<<NN/4, 256, 0, stream>>>(x, payA, offs, invc, W1, root1, b1, h1bf);
    fused32<0><<<NN/16, 512, 0, stream>>>(h1bf, payA, offs, invc, Bp2, b2, batch, h2bf, pooled, gcnt);
    fused64<1><<<NN/16, 512, 0, stream>>>(h2bf, payA, offs, invc, Bp3, b3, batch, h2bf, pooled, gcnt);
    head_k   <<<1, 128, 0, stream>>>(pooled, gcnt, fcw, fcb, out);
}